// Round 24
// baseline (513.512 us; speedup 1.0000x reference)
//
#include <hip/hip_runtime.h>
#include <hip/hip_bf16.h>
#include <math.h>

#define NN 50000
#define EE 800000
#define MM (EE + NN)   // edges + self loops
#define GG 64
#define SWG 512        // stat partial workgroups
#define NSB ((NN + 255) / 256)   // scan blocks = 196
#define PSP 16         // pooling splits per group

typedef __attribute__((ext_vector_type(8))) short short8v;
typedef __attribute__((ext_vector_type(4))) float float4v;

// adaptive int read: handles both int32 and int64 device buffers
__device__ __forceinline__ int geti(const void* p, long idx, int is64) {
    return is64 ? (int)((const long long*)p)[idx] : ((const int*)p)[idx];
}

__device__ __forceinline__ float bf2f(unsigned short u) {
    return __uint_as_float(((unsigned)u) << 16);
}

__device__ __forceinline__ unsigned short f2bf(float f) {
    __hip_bfloat16 t = __float2bfloat16(f);
    return *reinterpret_cast<unsigned short*>(&t);
}

__device__ __forceinline__ float eluf(float z) {
    return z > 0.f ? z : expm1f(z);
}

// ---------------- zero + detect + packW fused ----------------
// Wpk[L][ks][ct][lane][8]: lane l, elem j -> W[L][ks*32 + (l>>4)*8 + j][ct*16 + (l&15)]

__global__ void k_zero(int* p, int n, const int* __restrict__ ei, int* __restrict__ flag,
                       const float* __restrict__ W, unsigned short* __restrict__ Wpk) {
    int i = blockIdx.x * blockDim.x + threadIdx.x;
    if (i < n) p[i] = 0;
    if (i == 0 && ei != nullptr) {
        int ok = 1;
        for (int k = 0; k < 128; ++k) {
            int lo = ei[2 * k], hi = ei[2 * k + 1];
            if (hi != 0 || (unsigned)lo >= (unsigned)NN) { ok = 0; break; }
        }
        flag[0] = ok;
    }
    if (i < 3 * 2048 && Wpk != nullptr) {
        int l = i & 63, ct = (i >> 6) & 7, ks = (i >> 9) & 3, L = i >> 11;
        const float* Wb = W + L * 16384;
        int c = ct * 16 + (l & 15);
        int kbase = ks * 32 + (l >> 4) * 8;
        unsigned short v[8];
#pragma unroll
        for (int j = 0; j < 8; ++j) v[j] = f2bf(Wb[(kbase + j) * 128 + c]);
        *(uint4*)(Wpk + (size_t)i * 8) = *(uint4*)v;
    }
}

__global__ void k_count(const void* __restrict__ ei, const int* __restrict__ flag,
                        int* __restrict__ counts) {
    int e = blockIdx.x * blockDim.x + threadIdx.x;
    if (e >= MM) return;
    int is64 = flag[0];
    int d = (e < EE) ? geti(ei, (long)EE + e, is64) : (e - EE);
    if ((unsigned)d < (unsigned)NN) atomicAdd(&counts[d], 1);
}

// parallel scan: per-block inclusive scan + block sums
__global__ __launch_bounds__(256) void k_scan1(const int* __restrict__ counts,
                                               int* __restrict__ rowptr,
                                               int* __restrict__ bsum) {
    __shared__ int buf[256];
    int b = blockIdx.x, tid = threadIdx.x;
    int i = b * 256 + tid;
    int v = (i < NN) ? counts[i] : 0;
    buf[tid] = v;
    __syncthreads();
    for (int off = 1; off < 256; off <<= 1) {
        int t = (tid >= off) ? buf[tid - off] : 0;
        __syncthreads();
        buf[tid] += t;
        __syncthreads();
    }
    if (i < NN) rowptr[i + 1] = buf[tid];
    if (tid == 255) bsum[b] = buf[255];
}

__global__ __launch_bounds__(256) void k_scan2(int* __restrict__ bsum) {
    __shared__ int buf[256];
    int tid = threadIdx.x;
    int v = (tid < NSB) ? bsum[tid] : 0;
    buf[tid] = v;
    __syncthreads();
    for (int off = 1; off < 256; off <<= 1) {
        int t = (tid >= off) ? buf[tid - off] : 0;
        __syncthreads();
        buf[tid] += t;
        __syncthreads();
    }
    if (tid < NSB) bsum[tid] = (tid == 0) ? 0 : buf[tid - 1];
}

__global__ __launch_bounds__(256) void k_scan3(int* __restrict__ rowptr,
                                               const int* __restrict__ bsum) {
    int b = blockIdx.x, tid = threadIdx.x;
    int i = b * 256 + tid;
    if (i < NN) rowptr[i + 1] += bsum[b];
    if (b == 0 && tid == 0) rowptr[0] = 0;
}

// 4 edges per thread, phased (loads / atomics / stores) for ILP;
// non-temporal colv stores to avoid partial-dirty-line L2 thrash.
#define FILLB 832   // blocks: 832*256*4 = 851968 >= MM

__global__ __launch_bounds__(256) void k_fill(const void* __restrict__ ei,
                                              const int* __restrict__ flag,
                                              const int* __restrict__ rowptr,
                                              int* __restrict__ fill,
                                              int* __restrict__ colv) {
    const int T = FILLB * 256;
    int base = blockIdx.x * 256 + threadIdx.x;
    int is64 = flag[0];
    int ss[4], dd[4], ok[4];
#pragma unroll
    for (int u = 0; u < 4; ++u) {
        long e = base + (long)u * T;
        ok[u] = 0;
        if (e < MM) {
            int s, d;
            if (e < EE) { s = geti(ei, e, is64); d = geti(ei, (long)EE + e, is64); }
            else { s = d = (int)(e - EE); }
            if ((unsigned)d < (unsigned)NN && (unsigned)s < (unsigned)NN) {
                ss[u] = s; dd[u] = d; ok[u] = 1;
            }
        }
    }
    int pos[4];
#pragma unroll
    for (int u = 0; u < 4; ++u)
        if (ok[u]) pos[u] = rowptr[dd[u]] + atomicAdd(&fill[dd[u]], 1);
#pragma unroll
    for (int u = 0; u < 4; ++u)
        if (ok[u] && (unsigned)pos[u] < (unsigned)MM)
            __builtin_nontemporal_store(ss[u], &colv[pos[u]]);
}

// ---------------- MFMA GEMM + attention dots (bf16 xp out) ----------------
// block = 256 thr = 4 waves; block covers 64 rows; wave = 16-row strip.
// A-frag from LDS Hb[64][136] bf16; B-frag from Wpk (coalesced, L2-hot).
// C/D layout: col = lane&15, row = (lane>>4)*4 + reg.

__global__ __launch_bounds__(256) void k_gemm_att(
    const float* __restrict__ hsrc, const float* __restrict__ Ysrc,
    const float* __restrict__ st, const unsigned short* __restrict__ Wpk,
    const float* __restrict__ attS, const float* __restrict__ attD,
    unsigned short* __restrict__ xpb, float* __restrict__ als,
    float* __restrict__ ald, int n)
{
    __shared__ unsigned short Hb[64][136];
    int tid = threadIdx.x;
    int wv = tid >> 6, lane = tid & 63;
    int rbase = blockIdx.x * 64;
    bool useY = (Ysrc != nullptr);

#pragma unroll
    for (int i = 0; i < 8; ++i) {
        int idx = i * 256 + tid;
        int row = idx >> 5;
        int kq = (idx & 31) * 4;
        int gr = rbase + row;
        float4 v = make_float4(0.f, 0.f, 0.f, 0.f);
        if (gr < n) {
            if (useY) {
                float4 yv = *(const float4*)&Ysrc[(size_t)gr * 128 + kq];
                float4 scv = *(const float4*)&st[kq];
                float4 shv = *(const float4*)&st[128 + kq];
                v.x = eluf(fmaf(yv.x, scv.x, shv.x));
                v.y = eluf(fmaf(yv.y, scv.y, shv.y));
                v.z = eluf(fmaf(yv.z, scv.z, shv.z));
                v.w = eluf(fmaf(yv.w, scv.w, shv.w));
            } else {
                v = *(const float4*)&hsrc[(size_t)gr * 128 + kq];
            }
        }
        ushort4 b;
        b.x = f2bf(v.x); b.y = f2bf(v.y); b.z = f2bf(v.z); b.w = f2bf(v.w);
        *(ushort4*)&Hb[row][kq] = b;
    }
    __syncthreads();

    int g = lane >> 4, c15 = lane & 15;

    float4v acc[8];
#pragma unroll
    for (int ct = 0; ct < 8; ++ct) acc[ct] = (float4v)(0.f);

#pragma unroll
    for (int ks = 0; ks < 4; ++ks) {
        short8v a = *(const short8v*)&Hb[wv * 16 + c15][ks * 32 + g * 8];
#pragma unroll
        for (int ct = 0; ct < 8; ++ct) {
            short8v b = *(const short8v*)(Wpk + (((size_t)(ks * 8 + ct) * 64 + lane) * 8));
            acc[ct] = __builtin_amdgcn_mfma_f32_16x16x32_bf16(a, b, acc[ct], 0, 0, 0);
        }
    }

#pragma unroll
    for (int ct = 0; ct < 8; ++ct) {
        float as_ = attS[ct * 16 + c15];
        float ad_ = attD[ct * 16 + c15];
#pragma unroll
        for (int r = 0; r < 4; ++r) {
            int row = rbase + wv * 16 + g * 4 + r;
            float val = acc[ct][r];
            if (row < n) xpb[(size_t)row * 128 + ct * 16 + c15] = f2bf(val);
            float ds = val * as_;
            float dd = val * ad_;
            ds += __shfl_xor(ds, 1); ds += __shfl_xor(ds, 2);
            ds += __shfl_xor(ds, 4); ds += __shfl_xor(ds, 8);
            dd += __shfl_xor(dd, 1); dd += __shfl_xor(dd, 2);
            dd += __shfl_xor(dd, 4); dd += __shfl_xor(dd, 8);
            if (c15 == 0 && row < n) {
                als[row * 8 + ct] = ds;
                ald[row * 8 + ct] = dd;
            }
        }
    }
}

// ---------------- fused wave-per-node softmax + gather (shfl + prefetch) ----------------

__global__ __launch_bounds__(256) void k_agg(
    const unsigned short* __restrict__ xpb, const float* __restrict__ als,
    const float* __restrict__ ald,
    const int* __restrict__ rowptr, const int* __restrict__ colv,
    const float* __restrict__ prevRaw, const float* __restrict__ prevY,
    const float* __restrict__ pst, const float* __restrict__ bias,
    float* __restrict__ y, int n)
{
    int wid = (int)((blockIdx.x * blockDim.x + threadIdx.x) >> 6);
    int lane = threadIdx.x & 63;
    if (wid >= n) return;
    int rs = rowptr[wid], re = rowptr[wid + 1];
    int deg = re - rs;

    int hd = lane & 7;
    int ee = lane >> 3;
    float aldn = ald[wid * 8 + hd];
    int q = ee;
    int c0 = lane * 2;

    float a0 = 0.f, a1 = 0.f, smloc = 0.f;
    int full = deg & ~7;

    int se = 0; float va = 0.f;
    if (full > 0) {
        se = colv[rs + ee];
        va = als[se * 8 + hd];
    }

    for (int b0 = 0; b0 < full; b0 += 8) {
        int se_n = 0; float va_n = 0.f;
        if (b0 + 8 < full) {
            se_n = colv[rs + b0 + 8 + ee];
            va_n = als[se_n * 8 + hd];
        }
        float v = va + aldn;
        v = v > 0.f ? v : 0.2f * v;
        float al = expf(v);
        smloc += al;
#pragma unroll
        for (int j = 0; j < 8; ++j) {
            float a = __shfl(al, j * 8 + q);
            int s = __shfl(se, j * 8);
            ushort2 xv = *(const ushort2*)(xpb + (size_t)s * 128 + c0);
            a0 = fmaf(a, bf2f(xv.x), a0);
            a1 = fmaf(a, bf2f(xv.y), a1);
        }
        se = se_n; va = va_n;
    }

    if (full < deg) {
        int nb = deg - full;
        float al = 0.f;
        int se2 = 0;
        if (ee < nb) {
            se2 = colv[rs + full + ee];
            float v = als[se2 * 8 + hd] + aldn;
            v = v > 0.f ? v : 0.2f * v;
            al = expf(v);
            smloc += al;
        }
        for (int j = 0; j < nb; ++j) {
            float a = __shfl(al, j * 8 + q);
            int s = __shfl(se2, j * 8);
            ushort2 xv = *(const ushort2*)(xpb + (size_t)s * 128 + c0);
            a0 = fmaf(a, bf2f(xv.x), a0);
            a1 = fmaf(a, bf2f(xv.y), a1);
        }
    }

    smloc += __shfl_xor(smloc, 8);
    smloc += __shfl_xor(smloc, 16);
    smloc += __shfl_xor(smloc, 32);
    float inv = 1.f / __shfl(smloc, q);
    a0 *= inv;
    a1 *= inv;

    float p0 = 0.f, p1 = 0.f;
    if (prevY) {
        float2 yv = *(const float2*)(prevY + (size_t)wid * 128 + c0);
        p0 = eluf(fmaf(yv.x, pst[c0], pst[128 + c0]));
        p1 = eluf(fmaf(yv.y, pst[c0 + 1], pst[129 + c0]));
    } else if (prevRaw) {
        p0 = prevRaw[(size_t)wid * 128 + c0];
        p1 = prevRaw[(size_t)wid * 128 + c0 + 1];
    }
    y[wid * 128 + c0] = p0 + a0 + bias[c0];
    y[wid * 128 + c0 + 1] = p1 + a1 + bias[c0 + 1];
}

// ---------------- layernorm over axis 0 ----------------

__global__ __launch_bounds__(256) void k_stats(const float* __restrict__ y,
                                               double* __restrict__ partial, int n) {
    int col = threadIdx.x & 127;
    int rg = threadIdx.x >> 7;
    double s = 0.0, s2 = 0.0;
    for (int r = blockIdx.x * 2 + rg; r < n; r += SWG * 2) {
        float v = y[r * 128 + col];
        s += v; s2 += (double)v * (double)v;
    }
    __shared__ double ls[256], ls2[256];
    ls[threadIdx.x] = s; ls2[threadIdx.x] = s2;
    __syncthreads();
    if (rg == 0) {
        s += ls[threadIdx.x + 128];
        s2 += ls2[threadIdx.x + 128];
        partial[col * SWG + blockIdx.x] = s;
        partial[128 * SWG + col * SWG + blockIdx.x] = s2;
    }
}

// finishes stats AND bakes gamma/beta into affine scale/shift
__global__ void k_stats_fin(const double* __restrict__ partial,
                            const float* __restrict__ gamma,
                            const float* __restrict__ beta,
                            float* __restrict__ st, int n) {
    int col = threadIdx.x;  // 128 threads
    double s = 0.0, s2 = 0.0;
    for (int w = 0; w < SWG; ++w) {
        s += partial[col * SWG + w];
        s2 += partial[128 * SWG + col * SWG + w];
    }
    double mu = s / n;
    double var = s2 / n - mu * mu;
    double rsig = 1.0 / sqrt(var + 1e-5);
    double sc = (double)gamma[col] * rsig;
    st[col] = (float)sc;
    st[128 + col] = (float)((double)beta[col] - mu * sc);
}

// ---------------- pooling: split stage + reduce/readout ----------------

__global__ __launch_bounds__(256) void k_pool_part(
    const float* __restrict__ Y, const float* __restrict__ st,
    const void* __restrict__ batch, const int* __restrict__ flag,
    float* __restrict__ ppart, int n)
{
    int g = blockIdx.x / PSP;
    int sp = blockIdx.x % PSP;
    int is64 = flag[0];
    int lo = 0, hi = n;
    while (lo < hi) { int mid = (lo + hi) >> 1; if (geti(batch, mid, is64) < g) lo = mid + 1; else hi = mid; }
    int start = lo;
    hi = n;
    while (lo < hi) { int mid = (lo + hi) >> 1; if (geti(batch, mid, is64) < g + 1) lo = mid + 1; else hi = mid; }
    int end = lo;
    int cnt = end - start;
    int slice = (cnt + PSP - 1) / PSP;
    int s0 = start + sp * slice;
    int s1 = s0 + slice; if (s1 > end) s1 = end;

    int col = threadIdx.x & 127;
    int half = threadIdx.x >> 7;
    float sc = st[col], sh = st[128 + col];
    float s = 0.f;
    for (int r = s0 + half; r < s1; r += 2)
        s += eluf(fmaf(Y[(size_t)r * 128 + col], sc, sh));
    __shared__ float ls[256];
    ls[threadIdx.x] = s;
    __syncthreads();
    if (half == 0) ppart[(g * PSP + sp) * 128 + col] = s + ls[col + 128];
}

__global__ __launch_bounds__(128) void k_pool_fin(
    const float* __restrict__ ppart, const void* __restrict__ batch,
    const int* __restrict__ flag, const float* __restrict__ row,
    const float* __restrict__ rob, float* __restrict__ out, int n)
{
    int g = blockIdx.x;
    int is64 = flag[0];
    int lo = 0, hi = n;
    while (lo < hi) { int mid = (lo + hi) >> 1; if (geti(batch, mid, is64) < g) lo = mid + 1; else hi = mid; }
    int start = lo;
    hi = n;
    while (lo < hi) { int mid = (lo + hi) >> 1; if (geti(batch, mid, is64) < g + 1) lo = mid + 1; else hi = mid; }
    int cnt = lo - start;

    int col = threadIdx.x;   // 128
    float s = 0.f;
#pragma unroll
    for (int sp = 0; sp < PSP; ++sp) s += ppart[(g * PSP + sp) * 128 + col];
    __shared__ float ls[128];
    ls[col] = s * (1.f / fmaxf((float)cnt, 1.f));
    __syncthreads();
    if (col < 2) {
        float acc = 0.f;
        for (int c = 0; c < 128; ++c) acc = fmaf(ls[c], row[c * 2 + col], acc);
        out[g * 2 + col] = acc + rob[col];
    }
}

// ---------------- launch ----------------

extern "C" void kernel_launch(void* const* d_in, const int* in_sizes, int n_in,
                              void* d_out, int out_size, void* d_ws, size_t ws_size,
                              hipStream_t stream) {
    const float* x     = (const float*)d_in[0];
    const void*  ei    = d_in[1];
    const void*  batch = d_in[2];
    const float* W     = (const float*)d_in[3];
    const float* attS  = (const float*)d_in[4];
    const float* attD  = (const float*)d_in[5];
    const float* bias  = (const float*)d_in[6];
    const float* gamma = (const float*)d_in[7];
    const float* beta  = (const float*)d_in[8];
    const float* row   = (const float*)d_in[9];
    const float* rob   = (const float*)d_in[10];
    float* out = (float*)d_out;

    char* wsb = (char*)d_ws;
    size_t off = 0;
    auto alloc = [&](size_t bytes) {
        void* p = wsb + off;
        off += (bytes + 255) & ~(size_t)255;
        return p;
    };
    int*    flag    = (int*)alloc(256);
    int*    rowptr  = (int*)alloc((size_t)(NN + 1) * 4);
    int*    cnts    = (int*)alloc((size_t)NN * 4 * 2);   // counts + fill
    int*    bsum    = (int*)alloc((size_t)256 * 4);
    int*    colv    = (int*)alloc((size_t)MM * 4);
    double* partial = (double*)alloc((size_t)128 * SWG * 2 * 8);
    float*  st1     = (float*)alloc(256 * 4);
    float*  st2     = (float*)alloc(256 * 4);
    float*  st3     = (float*)alloc(256 * 4);
    float*  ppart   = (float*)alloc((size_t)GG * PSP * 128 * 4);
    float*  ALS     = (float*)alloc((size_t)NN * 8 * 4);
    float*  ALD     = (float*)alloc((size_t)NN * 8 * 4);
    unsigned short* XPB = (unsigned short*)alloc((size_t)NN * 128 * 2);
    unsigned short* WPK = (unsigned short*)alloc((size_t)3 * 2048 * 8 * 2);
    float* Y1 = (float*)alloc((size_t)NN * 128 * 4);
    float* Y2 = (float*)alloc((size_t)NN * 128 * 4);
    float* Y3 = (float*)alloc((size_t)NN * 128 * 4);
    (void)ws_size; (void)in_sizes; (void)n_in; (void)out_size;

    int* fill = cnts + NN;
    const int GBM = (NN + 63) / 64;   // mfma gemm blocks (64 rows each)
    const int GA = (NN + 3) / 4;      // agg blocks (wave per node)

    hipLaunchKernelGGL(k_zero, dim3((2 * NN + 255) / 256), dim3(256), 0, stream,
                       cnts, 2 * NN, (const int*)ei, flag, W, WPK);
    hipLaunchKernelGGL(k_count, dim3((MM + 255) / 256), dim3(256), 0, stream, ei, flag, cnts);
    hipLaunchKernelGGL(k_scan1, dim3(NSB), dim3(256), 0, stream, cnts, rowptr, bsum);
    hipLaunchKernelGGL(k_scan2, dim3(1), dim3(256), 0, stream, bsum);
    hipLaunchKernelGGL(k_scan3, dim3(NSB), dim3(256), 0, stream, rowptr, bsum);
    hipLaunchKernelGGL(k_fill, dim3(FILLB), dim3(256), 0, stream, ei, flag, rowptr, fill, colv);

    // ---- layer 0: h = x (raw), prev = 0 ----
    hipLaunchKernelGGL(k_gemm_att, dim3(GBM), dim3(256), 0, stream,
                       x, (const float*)nullptr, (const float*)nullptr,
                       WPK, attS, attD, XPB, ALS, ALD, NN);
    hipLaunchKernelGGL(k_agg, dim3(GA), dim3(256), 0, stream,
                       XPB, ALS, ALD, rowptr, colv,
                       (const float*)nullptr, (const float*)nullptr, (const float*)nullptr,
                       bias, Y1, NN);
    hipLaunchKernelGGL(k_stats, dim3(SWG), dim3(256), 0, stream, Y1, partial, NN);
    hipLaunchKernelGGL(k_stats_fin, dim3(1), dim3(128), 0, stream, partial, gamma, beta, st1, NN);

    // ---- layer 1: h = E1(Y1), prev = x (raw) ----
    hipLaunchKernelGGL(k_gemm_att, dim3(GBM), dim3(256), 0, stream,
                       (const float*)nullptr, Y1, st1,
                       WPK + (size_t)2048 * 8, attS + 128, attD + 128, XPB, ALS, ALD, NN);
    hipLaunchKernelGGL(k_agg, dim3(GA), dim3(256), 0, stream,
                       XPB, ALS, ALD, rowptr, colv,
                       x, (const float*)nullptr, (const float*)nullptr,
                       bias + 128, Y2, NN);
    hipLaunchKernelGGL(k_stats, dim3(SWG), dim3(256), 0, stream, Y2, partial, NN);
    hipLaunchKernelGGL(k_stats_fin, dim3(1), dim3(128), 0, stream, partial, gamma + 128, beta + 128, st2, NN);

    // ---- layer 2: h = E2(Y2), prev = E1(Y1) ----
    hipLaunchKernelGGL(k_gemm_att, dim3(GBM), dim3(256), 0, stream,
                       (const float*)nullptr, Y2, st2,
                       WPK + (size_t)2 * 2048 * 8, attS + 256, attD + 256, XPB, ALS, ALD, NN);
    hipLaunchKernelGGL(k_agg, dim3(GA), dim3(256), 0, stream,
                       XPB, ALS, ALD, rowptr, colv,
                       (const float*)nullptr, Y1, st1,
                       bias + 256, Y3, NN);
    hipLaunchKernelGGL(k_stats, dim3(SWG), dim3(256), 0, stream, Y3, partial, NN);
    hipLaunchKernelGGL(k_stats_fin, dim3(1), dim3(128), 0, stream, partial, gamma + 256, beta + 256, st3, NN);

    // ---- pooling on E3(Y3) ----
    hipLaunchKernelGGL(k_pool_part, dim3(GG * PSP), dim3(256), 0, stream,
                       Y3, st3, batch, flag, ppart, NN);
    hipLaunchKernelGGL(k_pool_fin, dim3(GG), dim3(128), 0, stream,
                       ppart, batch, flag, row, rob, out, NN);
}

// Round 25
// 488.742 us; speedup vs baseline: 1.0507x; 1.0507x over previous
//
#include <hip/hip_runtime.h>
#include <hip/hip_bf16.h>
#include <math.h>

#define NN 50000
#define EE 800000
#define MM (EE + NN)   // edges + self loops
#define GG 64
#define SWG 512        // stat partial workgroups
#define NSB ((NN + 255) / 256)   // scan blocks = 196
#define PSP 16         // pooling splits per group

typedef __attribute__((ext_vector_type(8))) short short8v;
typedef __attribute__((ext_vector_type(4))) float float4v;

// adaptive int read: handles both int32 and int64 device buffers
__device__ __forceinline__ int geti(const void* p, long idx, int is64) {
    return is64 ? (int)((const long long*)p)[idx] : ((const int*)p)[idx];
}

__device__ __forceinline__ float bf2f(unsigned short u) {
    return __uint_as_float(((unsigned)u) << 16);
}

__device__ __forceinline__ unsigned short f2bf(float f) {
    __hip_bfloat16 t = __float2bfloat16(f);
    return *reinterpret_cast<unsigned short*>(&t);
}

__device__ __forceinline__ float eluf(float z) {
    return z > 0.f ? z : expm1f(z);
}

// ---------------- zero + detect + packW fused ----------------
// Wpk[L][ks][ct][lane][8]: lane l, elem j -> W[L][ks*32 + (l>>4)*8 + j][ct*16 + (l&15)]

__global__ void k_zero(int* p, int n, const int* __restrict__ ei, int* __restrict__ flag,
                       const float* __restrict__ W, unsigned short* __restrict__ Wpk) {
    int i = blockIdx.x * blockDim.x + threadIdx.x;
    if (i < n) p[i] = 0;
    if (i == 0 && ei != nullptr) {
        int ok = 1;
        for (int k = 0; k < 128; ++k) {
            int lo = ei[2 * k], hi = ei[2 * k + 1];
            if (hi != 0 || (unsigned)lo >= (unsigned)NN) { ok = 0; break; }
        }
        flag[0] = ok;
    }
    if (i < 3 * 2048 && Wpk != nullptr) {
        int l = i & 63, ct = (i >> 6) & 7, ks = (i >> 9) & 3, L = i >> 11;
        const float* Wb = W + L * 16384;
        int c = ct * 16 + (l & 15);
        int kbase = ks * 32 + (l >> 4) * 8;
        unsigned short v[8];
#pragma unroll
        for (int j = 0; j < 8; ++j) v[j] = f2bf(Wb[(kbase + j) * 128 + c]);
        *(uint4*)(Wpk + (size_t)i * 8) = *(uint4*)v;
    }
}

__global__ void k_count(const void* __restrict__ ei, const int* __restrict__ flag,
                        int* __restrict__ counts) {
    int e = blockIdx.x * blockDim.x + threadIdx.x;
    if (e >= MM) return;
    int is64 = flag[0];
    int d = (e < EE) ? geti(ei, (long)EE + e, is64) : (e - EE);
    if ((unsigned)d < (unsigned)NN) atomicAdd(&counts[d], 1);
}

// parallel scan: per-block inclusive scan + block sums
__global__ __launch_bounds__(256) void k_scan1(const int* __restrict__ counts,
                                               int* __restrict__ rowptr,
                                               int* __restrict__ bsum) {
    __shared__ int buf[256];
    int b = blockIdx.x, tid = threadIdx.x;
    int i = b * 256 + tid;
    int v = (i < NN) ? counts[i] : 0;
    buf[tid] = v;
    __syncthreads();
    for (int off = 1; off < 256; off <<= 1) {
        int t = (tid >= off) ? buf[tid - off] : 0;
        __syncthreads();
        buf[tid] += t;
        __syncthreads();
    }
    if (i < NN) rowptr[i + 1] = buf[tid];
    if (tid == 255) bsum[b] = buf[255];
}

__global__ __launch_bounds__(256) void k_scan2(int* __restrict__ bsum) {
    __shared__ int buf[256];
    int tid = threadIdx.x;
    int v = (tid < NSB) ? bsum[tid] : 0;
    buf[tid] = v;
    __syncthreads();
    for (int off = 1; off < 256; off <<= 1) {
        int t = (tid >= off) ? buf[tid - off] : 0;
        __syncthreads();
        buf[tid] += t;
        __syncthreads();
    }
    if (tid < NSB) bsum[tid] = (tid == 0) ? 0 : buf[tid - 1];
}

__global__ __launch_bounds__(256) void k_scan3(int* __restrict__ rowptr,
                                               const int* __restrict__ bsum) {
    int b = blockIdx.x, tid = threadIdx.x;
    int i = b * 256 + tid;
    if (i < NN) rowptr[i + 1] += bsum[b];
    if (b == 0 && tid == 0) rowptr[0] = 0;
}

// one edge per thread, plain stores (round-23 form: measured floor ~58 us)
__global__ void k_fill(const void* __restrict__ ei, const int* __restrict__ flag,
                       const int* __restrict__ rowptr,
                       int* __restrict__ fill, int* __restrict__ colv) {
    int e = blockIdx.x * blockDim.x + threadIdx.x;
    if (e >= MM) return;
    int is64 = flag[0];
    int s, d;
    if (e < EE) { s = geti(ei, e, is64); d = geti(ei, (long)EE + e, is64); }
    else { s = d = e - EE; }
    if ((unsigned)d >= (unsigned)NN || (unsigned)s >= (unsigned)NN) return;
    int pos = rowptr[d] + atomicAdd(&fill[d], 1);
    if ((unsigned)pos < (unsigned)MM) colv[pos] = s;
}

// ---------------- MFMA GEMM + attention dots (bf16 xp out) ----------------
// block = 256 thr = 4 waves; block covers 64 rows; wave = 16-row strip.
// A-frag from LDS Hb[64][136] bf16; B-frag from Wpk (coalesced, L2-hot).
// C/D layout: col = lane&15, row = (lane>>4)*4 + reg.

__global__ __launch_bounds__(256) void k_gemm_att(
    const float* __restrict__ hsrc, const float* __restrict__ Ysrc,
    const float* __restrict__ st, const unsigned short* __restrict__ Wpk,
    const float* __restrict__ attS, const float* __restrict__ attD,
    unsigned short* __restrict__ xpb, float* __restrict__ als,
    float* __restrict__ ald, int n)
{
    __shared__ unsigned short Hb[64][136];
    int tid = threadIdx.x;
    int wv = tid >> 6, lane = tid & 63;
    int rbase = blockIdx.x * 64;
    bool useY = (Ysrc != nullptr);

#pragma unroll
    for (int i = 0; i < 8; ++i) {
        int idx = i * 256 + tid;
        int row = idx >> 5;
        int kq = (idx & 31) * 4;
        int gr = rbase + row;
        float4 v = make_float4(0.f, 0.f, 0.f, 0.f);
        if (gr < n) {
            if (useY) {
                float4 yv = *(const float4*)&Ysrc[(size_t)gr * 128 + kq];
                float4 scv = *(const float4*)&st[kq];
                float4 shv = *(const float4*)&st[128 + kq];
                v.x = eluf(fmaf(yv.x, scv.x, shv.x));
                v.y = eluf(fmaf(yv.y, scv.y, shv.y));
                v.z = eluf(fmaf(yv.z, scv.z, shv.z));
                v.w = eluf(fmaf(yv.w, scv.w, shv.w));
            } else {
                v = *(const float4*)&hsrc[(size_t)gr * 128 + kq];
            }
        }
        ushort4 b;
        b.x = f2bf(v.x); b.y = f2bf(v.y); b.z = f2bf(v.z); b.w = f2bf(v.w);
        *(ushort4*)&Hb[row][kq] = b;
    }
    __syncthreads();

    int g = lane >> 4, c15 = lane & 15;

    float4v acc[8];
#pragma unroll
    for (int ct = 0; ct < 8; ++ct) acc[ct] = (float4v)(0.f);

#pragma unroll
    for (int ks = 0; ks < 4; ++ks) {
        short8v a = *(const short8v*)&Hb[wv * 16 + c15][ks * 32 + g * 8];
#pragma unroll
        for (int ct = 0; ct < 8; ++ct) {
            short8v b = *(const short8v*)(Wpk + (((size_t)(ks * 8 + ct) * 64 + lane) * 8));
            acc[ct] = __builtin_amdgcn_mfma_f32_16x16x32_bf16(a, b, acc[ct], 0, 0, 0);
        }
    }

#pragma unroll
    for (int ct = 0; ct < 8; ++ct) {
        float as_ = attS[ct * 16 + c15];
        float ad_ = attD[ct * 16 + c15];
#pragma unroll
        for (int r = 0; r < 4; ++r) {
            int row = rbase + wv * 16 + g * 4 + r;
            float val = acc[ct][r];
            if (row < n) xpb[(size_t)row * 128 + ct * 16 + c15] = f2bf(val);
            float ds = val * as_;
            float dd = val * ad_;
            ds += __shfl_xor(ds, 1); ds += __shfl_xor(ds, 2);
            ds += __shfl_xor(ds, 4); ds += __shfl_xor(ds, 8);
            dd += __shfl_xor(dd, 1); dd += __shfl_xor(dd, 2);
            dd += __shfl_xor(dd, 4); dd += __shfl_xor(dd, 8);
            if (c15 == 0 && row < n) {
                als[row * 8 + ct] = ds;
                ald[row * 8 + ct] = dd;
            }
        }
    }
}

// ---------------- fused wave-per-node softmax + gather (shfl + prefetch) ----------------

__global__ __launch_bounds__(256) void k_agg(
    const unsigned short* __restrict__ xpb, const float* __restrict__ als,
    const float* __restrict__ ald,
    const int* __restrict__ rowptr, const int* __restrict__ colv,
    const float* __restrict__ prevRaw, const float* __restrict__ prevY,
    const float* __restrict__ pst, const float* __restrict__ bias,
    float* __restrict__ y, int n)
{
    int wid = (int)((blockIdx.x * blockDim.x + threadIdx.x) >> 6);
    int lane = threadIdx.x & 63;
    if (wid >= n) return;
    int rs = rowptr[wid], re = rowptr[wid + 1];
    int deg = re - rs;

    int hd = lane & 7;
    int ee = lane >> 3;
    float aldn = ald[wid * 8 + hd];
    int q = ee;
    int c0 = lane * 2;

    float a0 = 0.f, a1 = 0.f, smloc = 0.f;
    int full = deg & ~7;

    int se = 0; float va = 0.f;
    if (full > 0) {
        se = colv[rs + ee];
        va = als[se * 8 + hd];
    }

    for (int b0 = 0; b0 < full; b0 += 8) {
        int se_n = 0; float va_n = 0.f;
        if (b0 + 8 < full) {
            se_n = colv[rs + b0 + 8 + ee];
            va_n = als[se_n * 8 + hd];
        }
        float v = va + aldn;
        v = v > 0.f ? v : 0.2f * v;
        float al = expf(v);
        smloc += al;
#pragma unroll
        for (int j = 0; j < 8; ++j) {
            float a = __shfl(al, j * 8 + q);
            int s = __shfl(se, j * 8);
            ushort2 xv = *(const ushort2*)(xpb + (size_t)s * 128 + c0);
            a0 = fmaf(a, bf2f(xv.x), a0);
            a1 = fmaf(a, bf2f(xv.y), a1);
        }
        se = se_n; va = va_n;
    }

    if (full < deg) {
        int nb = deg - full;
        float al = 0.f;
        int se2 = 0;
        if (ee < nb) {
            se2 = colv[rs + full + ee];
            float v = als[se2 * 8 + hd] + aldn;
            v = v > 0.f ? v : 0.2f * v;
            al = expf(v);
            smloc += al;
        }
        for (int j = 0; j < nb; ++j) {
            float a = __shfl(al, j * 8 + q);
            int s = __shfl(se2, j * 8);
            ushort2 xv = *(const ushort2*)(xpb + (size_t)s * 128 + c0);
            a0 = fmaf(a, bf2f(xv.x), a0);
            a1 = fmaf(a, bf2f(xv.y), a1);
        }
    }

    smloc += __shfl_xor(smloc, 8);
    smloc += __shfl_xor(smloc, 16);
    smloc += __shfl_xor(smloc, 32);
    float inv = 1.f / __shfl(smloc, q);
    a0 *= inv;
    a1 *= inv;

    float p0 = 0.f, p1 = 0.f;
    if (prevY) {
        float2 yv = *(const float2*)(prevY + (size_t)wid * 128 + c0);
        p0 = eluf(fmaf(yv.x, pst[c0], pst[128 + c0]));
        p1 = eluf(fmaf(yv.y, pst[c0 + 1], pst[129 + c0]));
    } else if (prevRaw) {
        p0 = prevRaw[(size_t)wid * 128 + c0];
        p1 = prevRaw[(size_t)wid * 128 + c0 + 1];
    }
    y[wid * 128 + c0] = p0 + a0 + bias[c0];
    y[wid * 128 + c0 + 1] = p1 + a1 + bias[c0 + 1];
}

// ---------------- layernorm over axis 0 ----------------

__global__ __launch_bounds__(256) void k_stats(const float* __restrict__ y,
                                               double* __restrict__ partial, int n) {
    int col = threadIdx.x & 127;
    int rg = threadIdx.x >> 7;
    double s = 0.0, s2 = 0.0;
    for (int r = blockIdx.x * 2 + rg; r < n; r += SWG * 2) {
        float v = y[r * 128 + col];
        s += v; s2 += (double)v * (double)v;
    }
    __shared__ double ls[256], ls2[256];
    ls[threadIdx.x] = s; ls2[threadIdx.x] = s2;
    __syncthreads();
    if (rg == 0) {
        s += ls[threadIdx.x + 128];
        s2 += ls2[threadIdx.x + 128];
        partial[col * SWG + blockIdx.x] = s;
        partial[128 * SWG + col * SWG + blockIdx.x] = s2;
    }
}

// finishes stats AND bakes gamma/beta into affine scale/shift
__global__ void k_stats_fin(const double* __restrict__ partial,
                            const float* __restrict__ gamma,
                            const float* __restrict__ beta,
                            float* __restrict__ st, int n) {
    int col = threadIdx.x;  // 128 threads
    double s = 0.0, s2 = 0.0;
    for (int w = 0; w < SWG; ++w) {
        s += partial[col * SWG + w];
        s2 += partial[128 * SWG + col * SWG + w];
    }
    double mu = s / n;
    double var = s2 / n - mu * mu;
    double rsig = 1.0 / sqrt(var + 1e-5);
    double sc = (double)gamma[col] * rsig;
    st[col] = (float)sc;
    st[128 + col] = (float)((double)beta[col] - mu * sc);
}

// ---------------- pooling: split stage + reduce/readout ----------------

__global__ __launch_bounds__(256) void k_pool_part(
    const float* __restrict__ Y, const float* __restrict__ st,
    const void* __restrict__ batch, const int* __restrict__ flag,
    float* __restrict__ ppart, int n)
{
    int g = blockIdx.x / PSP;
    int sp = blockIdx.x % PSP;
    int is64 = flag[0];
    int lo = 0, hi = n;
    while (lo < hi) { int mid = (lo + hi) >> 1; if (geti(batch, mid, is64) < g) lo = mid + 1; else hi = mid; }
    int start = lo;
    hi = n;
    while (lo < hi) { int mid = (lo + hi) >> 1; if (geti(batch, mid, is64) < g + 1) lo = mid + 1; else hi = mid; }
    int end = lo;
    int cnt = end - start;
    int slice = (cnt + PSP - 1) / PSP;
    int s0 = start + sp * slice;
    int s1 = s0 + slice; if (s1 > end) s1 = end;

    int col = threadIdx.x & 127;
    int half = threadIdx.x >> 7;
    float sc = st[col], sh = st[128 + col];
    float s = 0.f;
    for (int r = s0 + half; r < s1; r += 2)
        s += eluf(fmaf(Y[(size_t)r * 128 + col], sc, sh));
    __shared__ float ls[256];
    ls[threadIdx.x] = s;
    __syncthreads();
    if (half == 0) ppart[(g * PSP + sp) * 128 + col] = s + ls[col + 128];
}

__global__ __launch_bounds__(128) void k_pool_fin(
    const float* __restrict__ ppart, const void* __restrict__ batch,
    const int* __restrict__ flag, const float* __restrict__ row,
    const float* __restrict__ rob, float* __restrict__ out, int n)
{
    int g = blockIdx.x;
    int is64 = flag[0];
    int lo = 0, hi = n;
    while (lo < hi) { int mid = (lo + hi) >> 1; if (geti(batch, mid, is64) < g) lo = mid + 1; else hi = mid; }
    int start = lo;
    hi = n;
    while (lo < hi) { int mid = (lo + hi) >> 1; if (geti(batch, mid, is64) < g + 1) lo = mid + 1; else hi = mid; }
    int cnt = lo - start;

    int col = threadIdx.x;   // 128
    float s = 0.f;
#pragma unroll
    for (int sp = 0; sp < PSP; ++sp) s += ppart[(g * PSP + sp) * 128 + col];
    __shared__ float ls[128];
    ls[col] = s * (1.f / fmaxf((float)cnt, 1.f));
    __syncthreads();
    if (col < 2) {
        float acc = 0.f;
        for (int c = 0; c < 128; ++c) acc = fmaf(ls[c], row[c * 2 + col], acc);
        out[g * 2 + col] = acc + rob[col];
    }
}

// ---------------- launch ----------------

extern "C" void kernel_launch(void* const* d_in, const int* in_sizes, int n_in,
                              void* d_out, int out_size, void* d_ws, size_t ws_size,
                              hipStream_t stream) {
    const float* x     = (const float*)d_in[0];
    const void*  ei    = d_in[1];
    const void*  batch = d_in[2];
    const float* W     = (const float*)d_in[3];
    const float* attS  = (const float*)d_in[4];
    const float* attD  = (const float*)d_in[5];
    const float* bias  = (const float*)d_in[6];
    const float* gamma = (const float*)d_in[7];
    const float* beta  = (const float*)d_in[8];
    const float* row   = (const float*)d_in[9];
    const float* rob   = (const float*)d_in[10];
    float* out = (float*)d_out;

    char* wsb = (char*)d_ws;
    size_t off = 0;
    auto alloc = [&](size_t bytes) {
        void* p = wsb + off;
        off += (bytes + 255) & ~(size_t)255;
        return p;
    };
    int*    flag    = (int*)alloc(256);
    int*    rowptr  = (int*)alloc((size_t)(NN + 1) * 4);
    int*    cnts    = (int*)alloc((size_t)NN * 4 * 2);   // counts + fill
    int*    bsum    = (int*)alloc((size_t)256 * 4);
    int*    colv    = (int*)alloc((size_t)MM * 4);
    double* partial = (double*)alloc((size_t)128 * SWG * 2 * 8);
    float*  st1     = (float*)alloc(256 * 4);
    float*  st2     = (float*)alloc(256 * 4);
    float*  st3     = (float*)alloc(256 * 4);
    float*  ppart   = (float*)alloc((size_t)GG * PSP * 128 * 4);
    float*  ALS     = (float*)alloc((size_t)NN * 8 * 4);
    float*  ALD     = (float*)alloc((size_t)NN * 8 * 4);
    unsigned short* XPB = (unsigned short*)alloc((size_t)NN * 128 * 2);
    unsigned short* WPK = (unsigned short*)alloc((size_t)3 * 2048 * 8 * 2);
    float* Y1 = (float*)alloc((size_t)NN * 128 * 4);
    float* Y2 = (float*)alloc((size_t)NN * 128 * 4);
    float* Y3 = (float*)alloc((size_t)NN * 128 * 4);
    (void)ws_size; (void)in_sizes; (void)n_in; (void)out_size;

    int* fill = cnts + NN;
    const int GBM = (NN + 63) / 64;   // mfma gemm blocks (64 rows each)
    const int GA = (NN + 3) / 4;      // agg blocks (wave per node)

    hipLaunchKernelGGL(k_zero, dim3((2 * NN + 255) / 256), dim3(256), 0, stream,
                       cnts, 2 * NN, (const int*)ei, flag, W, WPK);
    hipLaunchKernelGGL(k_count, dim3((MM + 255) / 256), dim3(256), 0, stream, ei, flag, cnts);
    hipLaunchKernelGGL(k_scan1, dim3(NSB), dim3(256), 0, stream, cnts, rowptr, bsum);
    hipLaunchKernelGGL(k_scan2, dim3(1), dim3(256), 0, stream, bsum);
    hipLaunchKernelGGL(k_scan3, dim3(NSB), dim3(256), 0, stream, rowptr, bsum);
    hipLaunchKernelGGL(k_fill, dim3((MM + 255) / 256), dim3(256), 0, stream, ei, flag, rowptr, fill, colv);

    // ---- layer 0: h = x (raw), prev = 0 ----
    hipLaunchKernelGGL(k_gemm_att, dim3(GBM), dim3(256), 0, stream,
                       x, (const float*)nullptr, (const float*)nullptr,
                       WPK, attS, attD, XPB, ALS, ALD, NN);
    hipLaunchKernelGGL(k_agg, dim3(GA), dim3(256), 0, stream,
                       XPB, ALS, ALD, rowptr, colv,
                       (const float*)nullptr, (const float*)nullptr, (const float*)nullptr,
                       bias, Y1, NN);
    hipLaunchKernelGGL(k_stats, dim3(SWG), dim3(256), 0, stream, Y1, partial, NN);
    hipLaunchKernelGGL(k_stats_fin, dim3(1), dim3(128), 0, stream, partial, gamma, beta, st1, NN);

    // ---- layer 1: h = E1(Y1), prev = x (raw) ----
    hipLaunchKernelGGL(k_gemm_att, dim3(GBM), dim3(256), 0, stream,
                       (const float*)nullptr, Y1, st1,
                       WPK + (size_t)2048 * 8, attS + 128, attD + 128, XPB, ALS, ALD, NN);
    hipLaunchKernelGGL(k_agg, dim3(GA), dim3(256), 0, stream,
                       XPB, ALS, ALD, rowptr, colv,
                       x, (const float*)nullptr, (const float*)nullptr,
                       bias + 128, Y2, NN);
    hipLaunchKernelGGL(k_stats, dim3(SWG), dim3(256), 0, stream, Y2, partial, NN);
    hipLaunchKernelGGL(k_stats_fin, dim3(1), dim3(128), 0, stream, partial, gamma + 128, beta + 128, st2, NN);

    // ---- layer 2: h = E2(Y2), prev = E1(Y1) ----
    hipLaunchKernelGGL(k_gemm_att, dim3(GBM), dim3(256), 0, stream,
                       (const float*)nullptr, Y2, st2,
                       WPK + (size_t)2 * 2048 * 8, attS + 256, attD + 256, XPB, ALS, ALD, NN);
    hipLaunchKernelGGL(k_agg, dim3(GA), dim3(256), 0, stream,
                       XPB, ALS, ALD, rowptr, colv,
                       (const float*)nullptr, Y1, st1,
                       bias + 256, Y3, NN);
    hipLaunchKernelGGL(k_stats, dim3(SWG), dim3(256), 0, stream, Y3, partial, NN);
    hipLaunchKernelGGL(k_stats_fin, dim3(1), dim3(128), 0, stream, partial, gamma + 256, beta + 256, st3, NN);

    // ---- pooling on E3(Y3) ----
    hipLaunchKernelGGL(k_pool_part, dim3(GG * PSP), dim3(256), 0, stream,
                       Y3, st3, batch, flag, ppart, NN);
    hipLaunchKernelGGL(k_pool_fin, dim3(GG), dim3(128), 0, stream,
                       ppart, batch, flag, row, rob, out, NN);
}